// Round 5
// baseline (187.993 us; speedup 1.0000x reference)
//
#include <hip/hip_runtime.h>

typedef __attribute__((ext_vector_type(8))) short s8bf;    // 8 x bf16
typedef __attribute__((ext_vector_type(4))) float f4;
typedef __attribute__((ext_vector_type(16))) float f16f;   // 32x32 MFMA acc
typedef __attribute__((ext_vector_type(2))) unsigned u2;

#define HQ 32
#define HK 8
#define DH 128
#define LK 1024

static __device__ __forceinline__ unsigned pkbf(float a, float b) {
  unsigned ua = __builtin_bit_cast(unsigned, a) + 0x8000u;
  unsigned ub = __builtin_bit_cast(unsigned, b) + 0x8000u;
  return (ua >> 16) | (ub & 0xffff0000u);
}
union frag_u { s8bf v; unsigned u[4]; };

// ---------------- prepass: K -> bf16 [bg][key][d]; V -> bf16 tiled-T [bg][kt][d][64key] ----
__global__ void prep_kernel(const float* __restrict__ kg, const float* __restrict__ vg,
                            short* __restrict__ kbf, short* __restrict__ vtb) {
  const int blk = blockIdx.x;
  if (blk < 512) {
    const int tid0 = blk * 256 + threadIdx.x;
#pragma unroll
    for (int i = 0; i < 4; ++i) {
      int e = tid0 + i * 131072;
      int d = (e & 31) * 4;
      int key = (e >> 5) & 1023;
      int bg = e >> 15;
      int b = bg >> 3, g = bg & 7;
      f4 x = *(const f4*)(kg + (((size_t)(b * 1024 + key) * HK + g) * DH + d));
      u2 w; w[0] = pkbf(x[0], x[1]); w[1] = pkbf(x[2], x[3]);
      *(u2*)(kbf + ((size_t)bg * 1024 + key) * DH + d) = w;
    }
  } else {
    __shared__ short T[64 * 130];
    const int t = blk - 512;              // 0..255
    const int bg = t >> 4, kt = t & 15;
    const int b = bg >> 3, g = bg & 7;
#pragma unroll
    for (int i = 0; i < 8; ++i) {
      int e = threadIdx.x * 4 + i * 1024; // 64 keys x 128 d
      int key = e >> 7, d = e & 127;
      f4 x = *(const f4*)(vg + (((size_t)(b * 1024 + kt * 64 + key) * HK + g) * DH + d));
      u2 w; w[0] = pkbf(x[0], x[1]); w[1] = pkbf(x[2], x[3]);
      *(u2*)&T[key * 130 + d] = w;
    }
    __syncthreads();
#pragma unroll
    for (int i = 0; i < 16; ++i) {
      int j = threadIdx.x + i * 256;
      int r = j >> 5;                     // d 0..127
      int kgp = (j & 31) * 2;             // key pair
      unsigned lo = (unsigned short)T[kgp * 130 + r];
      unsigned hi = (unsigned short)T[(kgp + 1) * 130 + r];
      *(unsigned*)(vtb + (((size_t)(bg * 16 + kt) * DH + r) * 64 + kgp)) = lo | (hi << 16);
    }
  }
}

// ---------------- one 64-key tile step (barrier-free) ----------------
static __device__ __forceinline__ void attn_step(
    int nct, int domask,
    const short* __restrict__ ktile,   // K[key64][DH] bf16
    const short* __restrict__ vtile,   // V^T[d128][key64] bf16 (tiled)
    const s8bf (&qf)[8], int lane, float qsc,
    float& m_, float& l_, f16f (&oacc)[4]) {
  const int l32 = lane & 31, hl = lane >> 5;

  // ---- S^T = K Q^T : D[key][q], col=q=l32, row=(t&3)+8*(t>>2)+4*hl
  f16f sacc[2];
#pragma unroll
  for (int c = 0; c < 2; ++c) sacc[c] = (f16f)(0.0f);
#pragma unroll
  for (int s = 0; s < 8; ++s) {
#pragma unroll
    for (int c = 0; c < 2; ++c) {
      if (c < nct) {
        s8bf kf = *(const s8bf*)&ktile[(c * 32 + l32) * DH + s * 16 + hl * 8];
        sacc[c] = __builtin_amdgcn_mfma_f32_32x32x16_bf16(kf, qf[s], sacc[c], 0, 0, 0);
      }
    }
  }

  // ---- scale (exp2 domain) + causal mask on last ct-tile
#pragma unroll
  for (int c = 0; c < 2; ++c) if (c < nct) {
#pragma unroll
    for (int t = 0; t < 16; ++t) sacc[c][t] *= qsc;
  }
  if (domask) {
    int c = nct - 1;
#pragma unroll
    for (int t = 0; t < 16; ++t) {
      int rk = (t & 3) + 8 * (t >> 2) + 4 * hl;
      if (rk > l32) sacc[c][t] = -1e30f;
    }
  }

  // ---- online softmax (1 shuffle per reduction)
  float vmax = -1e30f;
#pragma unroll
  for (int c = 0; c < 2; ++c) if (c < nct)
#pragma unroll
    for (int t = 0; t < 16; ++t) vmax = fmaxf(vmax, sacc[c][t]);
  vmax = fmaxf(vmax, __shfl_xor(vmax, 32));
  float mn = fmaxf(m_, vmax);
  int upd = (mn > m_);
  float alpha = exp2f(m_ - mn);
  m_ = mn;

  float rs = 0.0f;
#pragma unroll
  for (int c = 0; c < 2; ++c) if (c < nct)
#pragma unroll
    for (int t = 0; t < 16; ++t) {
      float pv = exp2f(sacc[c][t] - mn);
      sacc[c][t] = pv;
      rs += pv;
    }
  rs += __shfl_xor(rs, 32);
  l_ = l_ * alpha + rs;
  if (__any(upd)) {
#pragma unroll
    for (int dt = 0; dt < 4; ++dt)
#pragma unroll
      for (int t = 0; t < 16; ++t) oacc[dt][t] *= alpha;
  }

  // ---- P^T B-frags via cross-half exchange, then O^T += V^T P^T
#pragma unroll
  for (int c = 0; c < 2; ++c) if (c < nct) {
#pragma unroll
    for (int s2 = 0; s2 < 2; ++s2) {
      unsigned pA0 = pkbf(sacc[c][8 * s2 + 0], sacc[c][8 * s2 + 1]);
      unsigned pA1 = pkbf(sacc[c][8 * s2 + 2], sacc[c][8 * s2 + 3]);
      unsigned pB0 = pkbf(sacc[c][8 * s2 + 4], sacc[c][8 * s2 + 5]);
      unsigned pB1 = pkbf(sacc[c][8 * s2 + 6], sacc[c][8 * s2 + 7]);
      unsigned xA0 = (unsigned)__shfl_xor((int)pA0, 32);
      unsigned xA1 = (unsigned)__shfl_xor((int)pA1, 32);
      unsigned xB0 = (unsigned)__shfl_xor((int)pB0, 32);
      unsigned xB1 = (unsigned)__shfl_xor((int)pB1, 32);
      frag_u pf;
      pf.u[0] = hl ? xB0 : pA0;
      pf.u[1] = hl ? xB1 : pA1;
      pf.u[2] = hl ? pB0 : xA0;
      pf.u[3] = hl ? pB1 : xA1;

      const short* vb = vtile + c * 32 + s2 * 16 + hl * 8;
#pragma unroll
      for (int dt = 0; dt < 4; ++dt) {
        s8bf vf = *(const s8bf*)&vb[(dt * 32 + l32) * 64];
        oacc[dt] = __builtin_amdgcn_mfma_f32_32x32x16_bf16(vf, pf.v, oacc[dt], 0, 0, 0);
      }
    }
  }
}

// ---------------- main: barrier-free, LDS-free streaming flash ----------------
__launch_bounds__(128, 3)
__global__ void fa_main(const float* __restrict__ qg, const short* __restrict__ kbf,
                        const short* __restrict__ vtb, float* __restrict__ out) {
  const int id  = blockIdx.x;            // 0..1023, id&7 = kv-head = XCD slot
  const int g   = id & 7;
  const int r   = id >> 3;               // 0..127
  const int qt  = 15 - (r >> 3);         // longest tasks first
  const int w3  = r & 7;
  const int sub = w3 & 1;
  const int hp  = (w3 >> 1) & 1;
  const int b   = (w3 >> 2) & 1;
  const int wave = threadIdx.x >> 6;
  const int lane = threadIdx.x & 63;
  const int l32  = lane & 31, hl = lane >> 5;
  const int h    = g * 4 + hp * 2 + wave;
  const int bg   = b * 8 + g;
  const int seq0 = b * 1024;
  const int qrow = qt * 64 + sub * 32 + l32;

  // ---- Q B-frags: n=q=l32, k(d) = s*16 + hl*8 + j
  const float* qp = qg + ((size_t)(seq0 + qrow) * HQ + h) * DH;
  s8bf qf[8];
#pragma unroll
  for (int s = 0; s < 8; ++s) {
    const float* p = qp + s * 16 + hl * 8;
    f4 a = *(const f4*)p, c = *(const f4*)(p + 4);
    frag_u t;
    t.u[0] = pkbf(a[0], a[1]); t.u[1] = pkbf(a[2], a[3]);
    t.u[2] = pkbf(c[0], c[1]); t.u[3] = pkbf(c[2], c[3]);
    qf[s] = t.v;
  }

  float m_ = -1e30f, l_ = 0.0f;
  f16f oacc[4];
#pragma unroll
  for (int dt = 0; dt < 4; ++dt) oacc[dt] = (f16f)(0.0f);

  const float qsc = 0.08838834764831845f * 1.4426950408889634f;

  const short* kb = kbf + (size_t)bg * LK * DH;
  const short* vb = vtb + (size_t)bg * 16 * DH * 64;

  for (int kt = 0; kt < qt; ++kt)
    attn_step(2, 0, kb + (size_t)kt * 64 * DH, vb + (size_t)kt * DH * 64,
              qf, lane, qsc, m_, l_, oacc);
  attn_step(sub ? 2 : 1, 1, kb + (size_t)qt * 64 * DH, vb + (size_t)qt * DH * 64,
            qf, lane, qsc, m_, l_, oacc);

  // ---- epilogue: lane holds O^T col q=l32, rows d = dt*32 + 8*grp + 4*hl + i
  float inv = 1.0f / l_;
  float* op = out + ((size_t)(seq0 + qrow) * HQ + h) * DH;
#pragma unroll
  for (int dt = 0; dt < 4; ++dt)
#pragma unroll
    for (int grp = 0; grp < 4; ++grp) {
      f4 w;
      w[0] = oacc[dt][grp * 4 + 0] * inv;
      w[1] = oacc[dt][grp * 4 + 1] * inv;
      w[2] = oacc[dt][grp * 4 + 2] * inv;
      w[3] = oacc[dt][grp * 4 + 3] * inv;
      *(f4*)(op + dt * 32 + grp * 8 + hl * 4) = w;
    }
}

extern "C" void kernel_launch(void* const* d_in, const int* in_sizes, int n_in,
                              void* d_out, int out_size, void* d_ws, size_t ws_size,
                              hipStream_t stream) {
  const float* q = (const float*)d_in[0];
  const float* k = (const float*)d_in[1];
  const float* v = (const float*)d_in[2];
  float* out = (float*)d_out;

  short* kbf = (short*)d_ws;                       // 16*1024*128 bf16 = 4 MB
  short* vtb = kbf + (size_t)16 * 1024 * 128;      // 4 MB (tiled V^T)

  prep_kernel<<<dim3(768), 256, 0, stream>>>(k, v, kbf, vtb);
  fa_main<<<dim3(1024), 128, 0, stream>>>(q, kbf, vtb, out);
}

// Round 6
// 164.578 us; speedup vs baseline: 1.1423x; 1.1423x over previous
//
#include <hip/hip_runtime.h>

typedef __attribute__((ext_vector_type(8))) short s8bf;    // 8 x bf16
typedef __attribute__((ext_vector_type(4))) float f4;
typedef __attribute__((ext_vector_type(2))) unsigned u2;
typedef __attribute__((ext_vector_type(4))) unsigned u4;

#define HQ 32
#define HK 8
#define DH 128

static __device__ __forceinline__ unsigned pkbf(float a, float b) {
  unsigned ua = __builtin_bit_cast(unsigned, a) + 0x8000u;
  unsigned ub = __builtin_bit_cast(unsigned, b) + 0x8000u;
  return (ua >> 16) | (ub & 0xffff0000u);
}
union frag_u { s8bf v; unsigned u[4]; };

// ---------------- prepass ----------------
// K -> bf16 fragment-major [bg][kt][f=ct*4+dk][lane] : lane cell = K[kt*64+ct*16+l16][dk*32+quad*8 +0..7]
// V -> bf16 fragment-major [bg][kt][f=dt*2+ks][lane] : lane cell = V^T[dt*16+l16][ks*32+quad*8 +0..7]
__global__ void prep_kernel(const float* __restrict__ kg, const float* __restrict__ vg,
                            short* __restrict__ kbt, short* __restrict__ vbt) {
  const int blk = blockIdx.x;
  if (blk < 512) {
    // K: 262144 cells of 16 B; 2 per thread
    const int gid = blk * 256 + threadIdx.x;
#pragma unroll
    for (int i = 0; i < 2; ++i) {
      int c = gid + i * 131072;
      int l16 = c & 15, quad = (c >> 4) & 3;
      int f = (c >> 6) & 15;
      int kt = (c >> 10) & 15;
      int bg = c >> 14;
      int b = bg >> 3, g = bg & 7;
      int key = kt * 64 + (f >> 2) * 16 + l16;
      int d0 = (f & 3) * 32 + quad * 8;
      const float* src = kg + (((size_t)(b * 1024 + key) * HK + g) * DH + d0);
      f4 a = *(const f4*)src, cc = *(const f4*)(src + 4);
      u4 w;
      w[0] = pkbf(a[0], a[1]);  w[1] = pkbf(a[2], a[3]);
      w[2] = pkbf(cc[0], cc[1]); w[3] = pkbf(cc[2], cc[3]);
      *(u4*)(kbt + (size_t)c * 8) = w;
    }
  } else {
    // V: one (bg,kt) 64x128 tile per block, transpose through LDS
    __shared__ short T[64 * 130];
    const int t = blk - 512;
    const int bg = t >> 4, kt = t & 15;
    const int b = bg >> 3, g = bg & 7;
#pragma unroll
    for (int i = 0; i < 8; ++i) {
      int e = threadIdx.x * 4 + i * 1024;   // 64 key x 128 d
      int key = e >> 7, d = e & 127;
      f4 x = *(const f4*)(vg + (((size_t)(b * 1024 + kt * 64 + key) * HK + g) * DH + d));
      u2 w; w[0] = pkbf(x[0], x[1]); w[1] = pkbf(x[2], x[3]);
      *(u2*)&T[key * 130 + d] = w;
    }
    __syncthreads();
    short* dst = vbt + (size_t)(bg * 16 + kt) * 8192;
#pragma unroll
    for (int i = 0; i < 4; ++i) {
      int c = threadIdx.x + i * 256;        // 1024 cells per tile
      int lane = c & 63, f = c >> 6;
      int d = (f >> 1) * 16 + (lane & 15);
      int key0 = (f & 1) * 32 + ((lane >> 4) & 3) * 8;
      u4 w;
#pragma unroll
      for (int p = 0; p < 4; ++p) {
        unsigned lo = (unsigned short)T[(key0 + 2 * p) * 130 + d];
        unsigned hi = (unsigned short)T[(key0 + 2 * p + 1) * 130 + d];
        w[p] = lo | (hi << 16);
      }
      *(u4*)(dst + (size_t)c * 8) = w;
    }
  }
}

// ---------------- main: barrier-free, LDS-free, fragment-streaming flash ----------------
__launch_bounds__(256, 4)
__global__ void fa_main(const float* __restrict__ qg, const short* __restrict__ kbt,
                        const short* __restrict__ vbt, float* __restrict__ out) {
  const int id  = blockIdx.x;            // 0..1023; id&7 -> XCD-aligned kv-head
  const int g   = id & 7;
  const int s   = id >> 3;
  const int qt  = 15 - (s >> 3);         // longest blocks dispatched first
  const int rem = s & 7;
  const int b   = rem >> 2;
  const int h   = g * 4 + (rem & 3);
  const int bg  = b * 8 + g;

  const int tid  = threadIdx.x;
  const int wave = tid >> 6, lane = tid & 63;
  const int l16  = lane & 15, quad = lane >> 4;
  const int qlocal = wave * 16 + l16;
  const int seq0 = b * 1024;

  // ---- Q fragment, softmax scale folded in (exp2 domain)
  const float qmul = 0.08838834764831845f * 1.4426950408889634f;
  const float* qp = qg + ((size_t)(seq0 + qt * 64 + qlocal) * HQ + h) * DH;
  s8bf qf[4];
#pragma unroll
  for (int dk = 0; dk < 4; ++dk) {
    const float* p = qp + dk * 32 + quad * 8;
    f4 a = *(const f4*)p, c = *(const f4*)(p + 4);
    frag_u t;
    t.u[0] = pkbf(a[0] * qmul, a[1] * qmul);
    t.u[1] = pkbf(a[2] * qmul, a[3] * qmul);
    t.u[2] = pkbf(c[0] * qmul, c[1] * qmul);
    t.u[3] = pkbf(c[2] * qmul, c[3] * qmul);
    qf[dk] = t.v;
  }

  float m_ = -1e30f, l_ = 0.0f;
  f4 oacc[8];
#pragma unroll
  for (int dt = 0; dt < 8; ++dt) oacc[dt] = (f4)(0.0f);

  const short* kbase = kbt + (size_t)bg * 16 * 8192 + lane * 8;
  const short* vbase = vbt + (size_t)bg * 16 * 8192 + lane * 8;

  for (int kt = 0; kt <= qt; ++kt) {
    const short* kp = kbase + (size_t)kt * 8192;
    const short* vp = vbase + (size_t)kt * 8192;

    // ---- S^T = K Q^T : 16 contiguous 1KB wave-reads, 4 independent 4-deep chains
    f4 sacc[4];
#pragma unroll
    for (int ct = 0; ct < 4; ++ct) sacc[ct] = (f4)(0.0f);
#pragma unroll
    for (int dk = 0; dk < 4; ++dk) {
#pragma unroll
      for (int ct = 0; ct < 4; ++ct) {
        s8bf kf = *(const s8bf*)&kp[(ct * 4 + dk) * 512];
        sacc[ct] = __builtin_amdgcn_mfma_f32_16x16x32_bf16(kf, qf[dk], sacc[ct], 0, 0, 0);
      }
    }

    // ---- causal mask on diagonal tile (scores already scaled via Q)
    if (kt == qt) {
#pragma unroll
      for (int ct = 0; ct < 4; ++ct)
#pragma unroll
        for (int i = 0; i < 4; ++i) {
          int key = ct * 16 + quad * 4 + i;
          if (key > qlocal) sacc[ct][i] = -1e30f;
        }
    }

    // ---- online softmax: 15 in-lane max + 2 shuffles
    float vmax = sacc[0][0];
#pragma unroll
    for (int ct = 0; ct < 4; ++ct)
#pragma unroll
      for (int i = 0; i < 4; ++i) vmax = fmaxf(vmax, sacc[ct][i]);
    vmax = fmaxf(vmax, __shfl_xor(vmax, 16));
    vmax = fmaxf(vmax, __shfl_xor(vmax, 32));
    float mn = fmaxf(m_, vmax);
    int upd = (mn > m_);
    float alpha = exp2f(m_ - mn);
    m_ = mn;

    float rs = 0.0f;
#pragma unroll
    for (int ct = 0; ct < 4; ++ct)
#pragma unroll
      for (int i = 0; i < 4; ++i) {
        float pv = exp2f(sacc[ct][i] - mn);
        sacc[ct][i] = pv;
        rs += pv;
      }
    rs += __shfl_xor(rs, 16);
    rs += __shfl_xor(rs, 32);
    l_ = l_ * alpha + rs;
    if (__any(upd)) {
#pragma unroll
      for (int dt = 0; dt < 8; ++dt)
#pragma unroll
        for (int i = 0; i < 4; ++i) oacc[dt][i] *= alpha;
    }

    // ---- pack P + in-register transpose to PV B-fragment
    unsigned pk[4][2];
#pragma unroll
    for (int ct = 0; ct < 4; ++ct) {
      pk[ct][0] = pkbf(sacc[ct][0], sacc[ct][1]);
      pk[ct][1] = pkbf(sacc[ct][2], sacc[ct][3]);
    }
    const int srcA = ((quad & 1) << 5) + l16;
    const int srcB = srcA + 16;
    const bool hi = (quad >> 1) != 0;

    // ---- O^T += V^T P^T : 16 contiguous 1KB wave-reads
#pragma unroll
    for (int ks = 0; ks < 2; ++ks) {
      frag_u fr;
#pragma unroll
      for (int w = 0; w < 2; ++w) {
        unsigned a0 = (unsigned)__shfl((int)pk[2 * ks][w], srcA);
        unsigned a1 = (unsigned)__shfl((int)pk[2 * ks + 1][w], srcA);
        fr.u[w] = hi ? a1 : a0;
        unsigned b0 = (unsigned)__shfl((int)pk[2 * ks][w], srcB);
        unsigned b1 = (unsigned)__shfl((int)pk[2 * ks + 1][w], srcB);
        fr.u[2 + w] = hi ? b1 : b0;
      }
#pragma unroll
      for (int dt = 0; dt < 8; ++dt) {
        s8bf vf = *(const s8bf*)&vp[(dt * 2 + ks) * 512];
        oacc[dt] = __builtin_amdgcn_mfma_f32_16x16x32_bf16(vf, fr.v, oacc[dt], 0, 0, 0);
      }
    }
  }

  // ---- epilogue: lane holds O^T[d=dt*16+quad*4+i][q=l16]
  float inv = 1.0f / l_;
  float* op = out + ((size_t)(seq0 + qt * 64 + qlocal) * HQ + h) * DH;
#pragma unroll
  for (int dt = 0; dt < 8; ++dt) {
    f4 w;
    w[0] = oacc[dt][0] * inv; w[1] = oacc[dt][1] * inv;
    w[2] = oacc[dt][2] * inv; w[3] = oacc[dt][3] * inv;
    *(f4*)(op + dt * 16 + quad * 4) = w;
  }
}

extern "C" void kernel_launch(void* const* d_in, const int* in_sizes, int n_in,
                              void* d_out, int out_size, void* d_ws, size_t ws_size,
                              hipStream_t stream) {
  const float* q = (const float*)d_in[0];
  const float* k = (const float*)d_in[1];
  const float* v = (const float*)d_in[2];
  float* out = (float*)d_out;

  short* kbt = (short*)d_ws;                       // 4 MB fragment-major K
  short* vbt = kbt + (size_t)16 * 16 * 8192;       // 4 MB fragment-major V^T

  prep_kernel<<<dim3(768), 256, 0, stream>>>(k, v, kbt, vbt);
  fa_main<<<dim3(1024), 256, 0, stream>>>(q, kbt, vbt, out);
}

// Round 8
// 154.471 us; speedup vs baseline: 1.2170x; 1.0654x over previous
//
#include <hip/hip_runtime.h>

typedef __attribute__((ext_vector_type(8))) short s8bf;    // 8 x bf16
typedef __attribute__((ext_vector_type(4))) float f4;
typedef __attribute__((ext_vector_type(2))) unsigned u2;
typedef __attribute__((ext_vector_type(4))) unsigned u4;

#define HQ 32
#define HK 8
#define DH 128

static __device__ __forceinline__ unsigned pkbf(float a, float b) {
  unsigned ua = __builtin_bit_cast(unsigned, a) + 0x8000u;
  unsigned ub = __builtin_bit_cast(unsigned, b) + 0x8000u;
  return (ua >> 16) | (ub & 0xffff0000u);
}
union frag_u { s8bf v; unsigned u[4]; };

// K stored in LOGICAL key order (round-6 layout). V stored with the key
// interleave that makes the S^T accumulator registers directly the PV
// B-fragment:  B-pos (ks,quad,j) -> logical key 32ks+quad*4+j (j<4),
//                                   32ks+16+quad*4+(j-4) (j>=4).

// ---------------- prepass ----------------
// K -> bf16 frag-major [bg][kt][f=ct*4+dk][lane]: lane cell = K[kt*64+ct*16+l16][dk*32+quad*8+0..7]
// V -> bf16 frag-major [bg][kt][f=dt*2+ks][lane]: lane cell j -> V[perm key][dt*16+l16]
__global__ void prep_kernel(const float* __restrict__ kg, const float* __restrict__ vg,
                            short* __restrict__ kbt, short* __restrict__ vbt) {
  const int blk = blockIdx.x;
  if (blk < 512) {
    const int gid = blk * 256 + threadIdx.x;
#pragma unroll
    for (int i = 0; i < 2; ++i) {
      int c = gid + i * 131072;
      int l16 = c & 15, quad = (c >> 4) & 3;
      int f = (c >> 6) & 15;
      int kt = (c >> 10) & 15;
      int bg = c >> 14;
      int b = bg >> 3, g = bg & 7;
      int key = kt * 64 + (f >> 2) * 16 + l16;
      int d0 = (f & 3) * 32 + quad * 8;
      const float* src = kg + (((size_t)(b * 1024 + key) * HK + g) * DH + d0);
      f4 a = *(const f4*)src, cc = *(const f4*)(src + 4);
      u4 w;
      w[0] = pkbf(a[0], a[1]);   w[1] = pkbf(a[2], a[3]);
      w[2] = pkbf(cc[0], cc[1]); w[3] = pkbf(cc[2], cc[3]);
      *(u4*)(kbt + (size_t)c * 8) = w;
    }
  } else {
    // V: one (bg,kt) 64x128 tile per block, transpose+interleave through LDS
    __shared__ short T[64 * 130];
    const int t = blk - 512;
    const int bg = t >> 4, kt = t & 15;
    const int b = bg >> 3, g = bg & 7;
#pragma unroll
    for (int i = 0; i < 8; ++i) {
      int e = threadIdx.x * 4 + i * 1024;   // 64 key x 128 d
      int key = e >> 7, d = e & 127;
      f4 x = *(const f4*)(vg + (((size_t)(b * 1024 + kt * 64 + key) * HK + g) * DH + d));
      u2 w; w[0] = pkbf(x[0], x[1]); w[1] = pkbf(x[2], x[3]);
      *(u2*)&T[key * 130 + d] = w;
    }
    __syncthreads();
    short* dst = vbt + (size_t)(bg * 16 + kt) * 8192;
#pragma unroll
    for (int i = 0; i < 4; ++i) {
      int c = threadIdx.x + i * 256;        // 1024 cells of 16B
      int lane = c & 63, f = c >> 6;        // f = dt*2+ks
      int l16 = lane & 15, quad = (lane >> 4) & 3;
      int dt = f >> 1, ks = f & 1;
      int d = dt * 16 + l16;
      int k0 = ks * 32 + quad * 4;          // keys for j=0..3
      int k1 = k0 + 16;                     // keys for j=4..7
      u4 w;
      w[0] = (unsigned)(unsigned short)T[(k0 + 0) * 130 + d] |
             ((unsigned)(unsigned short)T[(k0 + 1) * 130 + d] << 16);
      w[1] = (unsigned)(unsigned short)T[(k0 + 2) * 130 + d] |
             ((unsigned)(unsigned short)T[(k0 + 3) * 130 + d] << 16);
      w[2] = (unsigned)(unsigned short)T[(k1 + 0) * 130 + d] |
             ((unsigned)(unsigned short)T[(k1 + 1) * 130 + d] << 16);
      w[3] = (unsigned)(unsigned short)T[(k1 + 2) * 130 + d] |
             ((unsigned)(unsigned short)T[(k1 + 3) * 130 + d] << 16);
      *(u4*)(dst + (size_t)c * 8) = w;
    }
  }
}

// ---------------- main: barrier-free, LDS-free, shuffle-free-PV flash ----------------
__launch_bounds__(256, 4)
__global__ void fa_main(const float* __restrict__ qg, const short* __restrict__ kbt,
                        const short* __restrict__ vbt, float* __restrict__ out) {
  const int id  = blockIdx.x;            // 0..1023; id&7 -> XCD-aligned kv-head
  const int g   = id & 7;
  const int s   = id >> 3;
  const int qt  = 15 - (s >> 3);         // longest blocks dispatched first
  const int rem = s & 7;
  const int b   = rem >> 2;
  const int h   = g * 4 + (rem & 3);
  const int bg  = b * 8 + g;

  const int tid  = threadIdx.x;
  const int wave = tid >> 6, lane = tid & 63;
  const int l16  = lane & 15, quad = lane >> 4;
  const int qlocal = wave * 16 + l16;
  const int seq0 = b * 1024;

  // ---- Q fragment, softmax scale folded in (exp2 domain)
  const float qmul = 0.08838834764831845f * 1.4426950408889634f;
  const float* qp = qg + ((size_t)(seq0 + qt * 64 + qlocal) * HQ + h) * DH;
  s8bf qf[4];
#pragma unroll
  for (int dk = 0; dk < 4; ++dk) {
    const float* p = qp + dk * 32 + quad * 8;
    f4 a = *(const f4*)p, c = *(const f4*)(p + 4);
    frag_u t;
    t.u[0] = pkbf(a[0] * qmul, a[1] * qmul);
    t.u[1] = pkbf(a[2] * qmul, a[3] * qmul);
    t.u[2] = pkbf(c[0] * qmul, c[1] * qmul);
    t.u[3] = pkbf(c[2] * qmul, c[3] * qmul);
    qf[dk] = t.v;
  }

  float m_ = -1e30f, l_ = 0.0f;          // l_ is PER-LANE partial (reduced at epilogue)
  f4 oacc[8];
#pragma unroll
  for (int dt = 0; dt < 8; ++dt) oacc[dt] = (f4)(0.0f);

  const short* kbase = kbt + (size_t)bg * 16 * 8192 + lane * 8;
  const short* vbase = vbt + (size_t)bg * 16 * 8192 + lane * 8;

  for (int kt = 0; kt <= qt; ++kt) {
    const short* kp = kbase + (size_t)kt * 8192;
    const short* vp = vbase + (size_t)kt * 8192;

    // ---- prefetch V first half (frags 0..7 = dt 0..3)
    s8bf vfr0[8];
#pragma unroll
    for (int f = 0; f < 8; ++f) vfr0[f] = *(const s8bf*)&vp[f * 512];

    // ---- S^T = K Q^T : 16 contiguous 1KB wave-reads, 4 independent chains
    f4 sacc[4];
#pragma unroll
    for (int ct = 0; ct < 4; ++ct) sacc[ct] = (f4)(0.0f);
#pragma unroll
    for (int dk = 0; dk < 4; ++dk) {
#pragma unroll
      for (int ct = 0; ct < 4; ++ct) {
        s8bf kf = *(const s8bf*)&kp[(ct * 4 + dk) * 512];
        sacc[ct] = __builtin_amdgcn_mfma_f32_16x16x32_bf16(kf, qf[dk], sacc[ct], 0, 0, 0);
      }
    }

    // ---- prefetch V second half (frags 8..15 = dt 4..7)
    s8bf vfr1[8];
#pragma unroll
    for (int f = 0; f < 8; ++f) vfr1[f] = *(const s8bf*)&vp[(8 + f) * 512];

    // ---- causal mask on diagonal tile (logical key order)
    if (kt == qt) {
#pragma unroll
      for (int ct = 0; ct < 4; ++ct)
#pragma unroll
        for (int i = 0; i < 4; ++i) {
          int key = ct * 16 + quad * 4 + i;
          if (key > qlocal) sacc[ct][i] = -1e30f;
        }
    }

    // ---- online softmax: in-lane tree + 2 cross-lane max reduces
    float vmax = sacc[0][0];
#pragma unroll
    for (int ct = 0; ct < 4; ++ct)
#pragma unroll
      for (int i = 0; i < 4; ++i) vmax = fmaxf(vmax, sacc[ct][i]);
    vmax = fmaxf(vmax, __shfl_xor(vmax, 16));
    vmax = fmaxf(vmax, __shfl_xor(vmax, 32));
    float mn = fmaxf(m_, vmax);
    int upd = (mn > m_);
    float alpha = exp2f(m_ - mn);
    m_ = mn;

    float rs = 0.0f;
    unsigned pk[4][2];
#pragma unroll
    for (int ct = 0; ct < 4; ++ct) {
      float p0 = exp2f(sacc[ct][0] - mn);
      float p1 = exp2f(sacc[ct][1] - mn);
      float p2 = exp2f(sacc[ct][2] - mn);
      float p3 = exp2f(sacc[ct][3] - mn);
      rs += (p0 + p1) + (p2 + p3);
      pk[ct][0] = pkbf(p0, p1);
      pk[ct][1] = pkbf(p2, p3);
    }
    l_ = l_ * alpha + rs;                 // per-lane partial; reduced at epilogue
    if (__any(upd)) {
#pragma unroll
      for (int dt = 0; dt < 8; ++dt)
#pragma unroll
        for (int i = 0; i < 4; ++i) oacc[dt][i] *= alpha;
    }

    // ---- O^T += V^T P^T : B-fragment is a register rename of pk (no shuffles)
#pragma unroll
    for (int ks = 0; ks < 2; ++ks) {
      frag_u fr;
      fr.u[0] = pk[2 * ks][0];
      fr.u[1] = pk[2 * ks][1];
      fr.u[2] = pk[2 * ks + 1][0];
      fr.u[3] = pk[2 * ks + 1][1];
#pragma unroll
      for (int dt = 0; dt < 8; ++dt) {
        s8bf vf = (dt < 4) ? vfr0[dt * 2 + ks] : vfr1[(dt - 4) * 2 + ks];
        oacc[dt] = __builtin_amdgcn_mfma_f32_16x16x32_bf16(vf, fr.v, oacc[dt], 0, 0, 0);
      }
    }
  }

  // ---- epilogue: reduce l_, lane holds O^T[d=dt*16+quad*4+i][q=l16]
  float lt = l_;
  lt += __shfl_xor(lt, 16);
  lt += __shfl_xor(lt, 32);
  float inv = 1.0f / lt;
  float* op = out + ((size_t)(seq0 + qt * 64 + qlocal) * HQ + h) * DH;
#pragma unroll
  for (int dt = 0; dt < 8; ++dt) {
    f4 w;
    w[0] = oacc[dt][0] * inv; w[1] = oacc[dt][1] * inv;
    w[2] = oacc[dt][2] * inv; w[3] = oacc[dt][3] * inv;
    *(f4*)(op + dt * 16 + quad * 4) = w;
  }
}

extern "C" void kernel_launch(void* const* d_in, const int* in_sizes, int n_in,
                              void* d_out, int out_size, void* d_ws, size_t ws_size,
                              hipStream_t stream) {
  const float* q = (const float*)d_in[0];
  const float* k = (const float*)d_in[1];
  const float* v = (const float*)d_in[2];
  float* out = (float*)d_out;

  short* kbt = (short*)d_ws;                       // 4 MB fragment-major K (logical keys)
  short* vbt = kbt + (size_t)16 * 16 * 8192;       // 4 MB fragment-major V^T (interleaved keys)

  prep_kernel<<<dim3(768), 256, 0, stream>>>(k, v, kbt, vbt);
  fa_main<<<dim3(1024), 256, 0, stream>>>(q, kbt, vbt, out);
}